// Round 5
// baseline (1612.801 us; speedup 1.0000x reference)
//
#include <hip/hip_runtime.h>

// Grouped-expert SwiGLU (fp32 in/out) via bf16x3 split-fp32 MFMA emulation.
// v5 = v4 + sched_barrier(0) hardening at the barrier/waitcnt points.
//
// Prolog: all operands pre-split into packed, PRE-SWIZZLED bf16 hi|lo tile
// blocks. Per 128-row x 32-k tile, one contiguous 16KB block:
//   [r:128][chunk':8][8 elems]; elem (r, plane p, k) lives in chunk
//   c = p*4 + (k>>3), swizzled c' = c ^ (r & 7). 32 same-column readers then
//   spread uniformly over all banks (conflict-free ds_read_b128).
//   global_load_lds copies blocks verbatim (linear dest, swizzle baked at
//   pack time -- the m104/m173-compliant pattern).
// Stage 1 (512 thr, 8 waves 2x4, 64x32 wave tiles, 96KB LDS dbuf):
//   h = silu(x@G^T)*(x@U^T), epilogue writes h directly in packed form.
// Stage 2 (256 thr, 4 waves 2x2, 64x64 wave tiles, 64KB LDS dbuf):
//   out = h @ D^T.
// Both: counted-vmcnt double-buffer (s_waitcnt vmcnt(N), raw s_barrier, no
// full drains in the main loop) + s_setprio around MFMA clusters.

constexpr int DIM = 2048, HIDDEN = 1024, NE = 8, TOTAL = 16384;
constexpr int BM = 128, BN = 128, BK = 32;
constexpr int TBLK = 8192;  // ushorts per packed tile block (16 KB)

typedef __attribute__((ext_vector_type(8)))  short bf16x8;
typedef __attribute__((ext_vector_type(16))) float f32x16;
typedef unsigned short u16;

// Static device buffers (module-load allocated; no d_ws dependency).
__device__ u16 g_px[(size_t)(TOTAL / 128) * (DIM / 32) * TBLK];        // 128 MB
__device__ u16 g_pg[(size_t)(NE * HIDDEN / 128) * (DIM / 32) * TBLK];  //  64 MB
__device__ u16 g_pu[(size_t)(NE * HIDDEN / 128) * (DIM / 32) * TBLK];  //  64 MB
__device__ u16 g_pd[(size_t)(NE * DIM / 128) * (HIDDEN / 32) * TBLK];  //  64 MB
__device__ u16 g_ph[(size_t)(TOTAL / 128) * (HIDDEN / 32) * TBLK];     //  64 MB

__device__ __forceinline__ u16 bf16_rne(float f) {
  unsigned u = __builtin_bit_cast(unsigned, f);
  u += 0x7FFFu + ((u >> 16) & 1u);
  return (u16)(u >> 16);
}
__device__ __forceinline__ float bf16f(u16 s) {
  unsigned u = (unsigned)s << 16;
  return __builtin_bit_cast(float, u);
}
__device__ __forceinline__ void split2(float f, u16& hi, u16& lo) {
  hi = bf16_rne(f);
  lo = bf16_rne(f - bf16f(hi));
}

__device__ __forceinline__ void expert_range(const int* __restrict__ counts, int e,
                                             int& lo, int& nloc) {
  lo = 0; nloc = 0;
#pragma unroll
  for (int i = 0; i < NE; ++i) {
    int c = counts[i];
    if (i < e) lo += c;
    if (i == e) nloc = c;
  }
}

// global -> LDS, 16B per lane; per-lane global src, wave-uniform LDS dest.
__device__ __forceinline__ void stage16(const u16* g, u16* l) {
  __builtin_amdgcn_global_load_lds(
      (const __attribute__((address_space(1))) unsigned int*)g,
      (__attribute__((address_space(3))) unsigned int*)l, 16, 0, 0);
}

// ---------------- Prolog: fp32 -> packed swizzled bf16 hi|lo blocks ----------------
__global__ __launch_bounds__(256)
void pack_split(const float* __restrict__ src, u16* __restrict__ dst, int K, int n4) {
  int i = blockIdx.x * 256 + threadIdx.x;
  const int stride = gridDim.x * 256;
  const int ktiles = K >> 5;
  for (; i < n4; i += stride) {
    const float4 v = ((const float4*)src)[i];
    const int col = (i * 4) % K;
    const int row = (i * 4) / K;
    ushort4 h4, l4;
    split2(v.x, h4.x, l4.x);
    split2(v.y, h4.y, l4.y);
    split2(v.z, h4.z, l4.z);
    split2(v.w, h4.w, l4.w);
    const int r = row & 127, kk = col & 31;
    const size_t base = ((size_t)(row >> 7) * ktiles + (col >> 5)) * TBLK + r * 64;
    const int ch = (kk >> 3) ^ (r & 7);
    const int cl = ((kk >> 3) + 4) ^ (r & 7);
    *(ushort4*)(dst + base + ch * 8 + (kk & 7)) = h4;
    *(ushort4*)(dst + base + cl * 8 + (kk & 7)) = l4;
  }
}

// ---------------- Stage 1: h = silu(x@G^T) * (x@U^T) ----------------
__global__ __launch_bounds__(512, 2)
void moe_s1(const int* __restrict__ counts) {
  const int e = blockIdx.z;
  int lo, nloc;
  expert_range(counts, e, lo, nloc);
  const int m0 = blockIdx.x * BM;
  if (m0 >= nloc) return;
  const int n0 = blockIdx.y * BN;

  __shared__ __align__(16) u16 sm[2 * 3 * TBLK];  // 96 KB: 2 bufs x (A,G,U)

  const int tid = threadIdx.x, lane = tid & 63, w = tid >> 6;  // 8 waves
  const int wm = w >> 2, wnq = w & 3;  // wave tile 64x32 at (wm*64, wnq*32)

  const int gmt = (lo + m0) >> 7;
  const u16* const srcs[3] = {
      g_px + (size_t)gmt * (DIM / 32) * TBLK,
      g_pg + (size_t)(e * (HIDDEN / 128) + (n0 >> 7)) * (DIM / 32) * TBLK,
      g_pu + (size_t)(e * (HIDDEN / 128) + (n0 >> 7)) * (DIM / 32) * TBLK};

  // per-wave staging: 6 of 48 1KB-chunks (48 = 3 mats x 16 chunks)
  const u16* csrc[6];
  int coff[6];
#pragma unroll
  for (int j = 0; j < 6; ++j) {
    const int i = w * 6 + j;
    const int mat = i >> 4;
    const int off = (i & 15) * 512;
    csrc[j] = srcs[mat] + off + lane * 8;
    coff[j] = mat * TBLK + off;
  }

  auto stage = [&](int buf, int kt) {
#pragma unroll
    for (int j = 0; j < 6; ++j)
      stage16(csrc[j] + (size_t)kt * TBLK, &sm[buf * 3 * TBLK + coff[j]]);
  };

  auto frg = [&](int buf, int mat, int rbase, int p, int ks) -> bf16x8 {
    const int rr = rbase + (lane & 31);
    const int c = (p * 4 + ks * 2 + (lane >> 5)) ^ (rr & 7);
    return *(const bf16x8*)&sm[buf * 3 * TBLK + mat * TBLK + rr * 64 + c * 8];
  };

  f32x16 ag[2], au[2];
#pragma unroll
  for (int i = 0; i < 2; ++i)
#pragma unroll
    for (int k = 0; k < 16; ++k) { ag[i][k] = 0.f; au[i][k] = 0.f; }

  const int NT = DIM / BK;  // 64
  stage(0, 0);
  stage(1, 1);

  for (int kt = 0; kt < NT; ++kt) {
    const int b = kt & 1;
    // vmcnt(6): with in-order retirement, <=6 outstanding ==> tile kt's 6
    // loads retired (only tile kt+1's 6 may remain in flight).
    if (kt + 2 < NT) asm volatile("s_waitcnt vmcnt(6)" ::: "memory");
    else             asm volatile("s_waitcnt vmcnt(0)" ::: "memory");
    __builtin_amdgcn_s_barrier();
    __builtin_amdgcn_sched_barrier(0);  // pin: no LDS read crosses above
#pragma unroll
    for (int ks = 0; ks < 2; ++ks) {
      const bf16x8 aH0 = frg(b, 0, wm * 64,      0, ks);
      const bf16x8 aH1 = frg(b, 0, wm * 64 + 32, 0, ks);
      const bf16x8 aL0 = frg(b, 0, wm * 64,      1, ks);
      const bf16x8 aL1 = frg(b, 0, wm * 64 + 32, 1, ks);
      const bf16x8 gH = frg(b, 1, wnq * 32, 0, ks);
      const bf16x8 gL = frg(b, 1, wnq * 32, 1, ks);
      const bf16x8 uH = frg(b, 2, wnq * 32, 0, ks);
      const bf16x8 uL = frg(b, 2, wnq * 32, 1, ks);
      __builtin_amdgcn_s_setprio(1);
      ag[0] = __builtin_amdgcn_mfma_f32_32x32x16_bf16(aH0, gH, ag[0], 0, 0, 0);
      ag[0] = __builtin_amdgcn_mfma_f32_32x32x16_bf16(aH0, gL, ag[0], 0, 0, 0);
      ag[0] = __builtin_amdgcn_mfma_f32_32x32x16_bf16(aL0, gH, ag[0], 0, 0, 0);
      ag[1] = __builtin_amdgcn_mfma_f32_32x32x16_bf16(aH1, gH, ag[1], 0, 0, 0);
      ag[1] = __builtin_amdgcn_mfma_f32_32x32x16_bf16(aH1, gL, ag[1], 0, 0, 0);
      ag[1] = __builtin_amdgcn_mfma_f32_32x32x16_bf16(aL1, gH, ag[1], 0, 0, 0);
      au[0] = __builtin_amdgcn_mfma_f32_32x32x16_bf16(aH0, uH, au[0], 0, 0, 0);
      au[0] = __builtin_amdgcn_mfma_f32_32x32x16_bf16(aH0, uL, au[0], 0, 0, 0);
      au[0] = __builtin_amdgcn_mfma_f32_32x32x16_bf16(aL0, uH, au[0], 0, 0, 0);
      au[1] = __builtin_amdgcn_mfma_f32_32x32x16_bf16(aH1, uH, au[1], 0, 0, 0);
      au[1] = __builtin_amdgcn_mfma_f32_32x32x16_bf16(aH1, uL, au[1], 0, 0, 0);
      au[1] = __builtin_amdgcn_mfma_f32_32x32x16_bf16(aL1, uH, au[1], 0, 0, 0);
      __builtin_amdgcn_s_setprio(0);
    }
    __builtin_amdgcn_sched_barrier(0);  // pin: all LDS reads done before barrier
    __builtin_amdgcn_s_barrier();
    __builtin_amdgcn_sched_barrier(0);  // pin: stage loads stay below barrier
    if (kt + 2 < NT) stage(b, kt + 2);
  }

  // epilogue: h = silu(g)*u, written directly in packed swizzled hi|lo form.
  // C/D map: col=lane&31, row=(j&3)+8*(j>>2)+4*(lane>>5)
  const int hf = lane >> 5, ccol = lane & 31;
  const int n = n0 + wnq * 32 + ccol;
  const int kk = n & 31;
  const size_t hbase = ((size_t)gmt * (HIDDEN / 32) + (n >> 5)) * TBLK;
#pragma unroll
  for (int fm = 0; fm < 2; ++fm)
#pragma unroll
    for (int j = 0; j < 16; ++j) {
      const int rl = wm * 64 + fm * 32 + (j & 3) + ((j >> 2) << 3) + hf * 4;
      if (m0 + rl < nloc) {
        const float gv = ag[fm][j];
        const float uv = au[fm][j];
        const float hv = gv / (1.f + __expf(-gv)) * uv;
        u16 hh, hl;
        split2(hv, hh, hl);
        const int ch = (kk >> 3) ^ (rl & 7);
        const int cl = ((kk >> 3) + 4) ^ (rl & 7);
        g_ph[hbase + rl * 64 + ch * 8 + (kk & 7)] = hh;
        g_ph[hbase + rl * 64 + cl * 8 + (kk & 7)] = hl;
      }
    }
}

// ---------------- Stage 2: out = h @ D^T ----------------
__global__ __launch_bounds__(256, 2)
void moe_s2(const int* __restrict__ counts, float* __restrict__ out) {
  const int e = blockIdx.z;
  int lo, nloc;
  expert_range(counts, e, lo, nloc);
  const int m0 = blockIdx.x * BM;
  if (m0 >= nloc) return;
  const int n0 = blockIdx.y * BN;

  __shared__ __align__(16) u16 sm[2 * 2 * TBLK];  // 64 KB: 2 bufs x (A,B)

  const int tid = threadIdx.x, lane = tid & 63, w = tid >> 6;  // 4 waves
  const int wm = w >> 1, wn = w & 1;  // wave tile 64x64

  const int gmt = (lo + m0) >> 7;
  const u16* const srcs[2] = {
      g_ph + (size_t)gmt * (HIDDEN / 32) * TBLK,
      g_pd + (size_t)(e * (DIM / 128) + (n0 >> 7)) * (HIDDEN / 32) * TBLK};

  const u16* csrc[8];
  int coff[8];
#pragma unroll
  for (int j = 0; j < 8; ++j) {
    const int i = w * 8 + j;
    const int mat = i >> 4;
    const int off = (i & 15) * 512;
    csrc[j] = srcs[mat] + off + lane * 8;
    coff[j] = mat * TBLK + off;
  }

  auto stage = [&](int buf, int kt) {
#pragma unroll
    for (int j = 0; j < 8; ++j)
      stage16(csrc[j] + (size_t)kt * TBLK, &sm[buf * 2 * TBLK + coff[j]]);
  };

  auto frg = [&](int buf, int mat, int rbase, int p, int ks) -> bf16x8 {
    const int rr = rbase + (lane & 31);
    const int c = (p * 4 + ks * 2 + (lane >> 5)) ^ (rr & 7);
    return *(const bf16x8*)&sm[buf * 2 * TBLK + mat * TBLK + rr * 64 + c * 8];
  };

  f32x16 acc[2][2];
#pragma unroll
  for (int i = 0; i < 2; ++i)
#pragma unroll
    for (int j = 0; j < 2; ++j)
#pragma unroll
      for (int k = 0; k < 16; ++k) acc[i][j][k] = 0.f;

  const int NT = HIDDEN / BK;  // 32
  stage(0, 0);
  stage(1, 1);

  for (int kt = 0; kt < NT; ++kt) {
    const int b = kt & 1;
    if (kt + 2 < NT) asm volatile("s_waitcnt vmcnt(8)" ::: "memory");
    else             asm volatile("s_waitcnt vmcnt(0)" ::: "memory");
    __builtin_amdgcn_s_barrier();
    __builtin_amdgcn_sched_barrier(0);
#pragma unroll
    for (int ks = 0; ks < 2; ++ks) {
      bf16x8 aH[2], aL[2], bH[2], bL[2];
#pragma unroll
      for (int fm = 0; fm < 2; ++fm) {
        aH[fm] = frg(b, 0, wm * 64 + fm * 32, 0, ks);
        aL[fm] = frg(b, 0, wm * 64 + fm * 32, 1, ks);
      }
#pragma unroll
      for (int fn = 0; fn < 2; ++fn) {
        bH[fn] = frg(b, 1, wn * 64 + fn * 32, 0, ks);
        bL[fn] = frg(b, 1, wn * 64 + fn * 32, 1, ks);
      }
      __builtin_amdgcn_s_setprio(1);
#pragma unroll
      for (int fn = 0; fn < 2; ++fn)
#pragma unroll
        for (int fm = 0; fm < 2; ++fm) {
          acc[fm][fn] = __builtin_amdgcn_mfma_f32_32x32x16_bf16(aH[fm], bH[fn], acc[fm][fn], 0, 0, 0);
          acc[fm][fn] = __builtin_amdgcn_mfma_f32_32x32x16_bf16(aH[fm], bL[fn], acc[fm][fn], 0, 0, 0);
          acc[fm][fn] = __builtin_amdgcn_mfma_f32_32x32x16_bf16(aL[fm], bH[fn], acc[fm][fn], 0, 0, 0);
        }
      __builtin_amdgcn_s_setprio(0);
    }
    __builtin_amdgcn_sched_barrier(0);
    __builtin_amdgcn_s_barrier();
    __builtin_amdgcn_sched_barrier(0);
    if (kt + 2 < NT) stage(b, kt + 2);
  }

  const int hf = lane >> 5, ccol = lane & 31;
#pragma unroll
  for (int fm = 0; fm < 2; ++fm)
#pragma unroll
    for (int fn = 0; fn < 2; ++fn)
#pragma unroll
      for (int j = 0; j < 16; ++j) {
        const int rl = wm * 64 + fm * 32 + (j & 3) + ((j >> 2) << 3) + hf * 4;
        if (m0 + rl < nloc) {
          out[(size_t)(lo + m0 + rl) * DIM + (n0 + wn * 64 + fn * 32 + ccol)] = acc[fm][fn][j];
        }
      }
}

extern "C" void kernel_launch(void* const* d_in, const int* in_sizes, int n_in,
                              void* d_out, int out_size, void* d_ws, size_t ws_size,
                              hipStream_t stream) {
  const float* x    = (const float*)d_in[0];
  const float* gate = (const float*)d_in[1];
  const float* up   = (const float*)d_in[2];
  const float* down = (const float*)d_in[3];
  const int*   cnts = (const int*)d_in[4];
  float*       out  = (float*)d_out;
  (void)d_ws; (void)ws_size;

  u16 *px, *pg, *pu, *pd;
  hipGetSymbolAddress((void**)&px, HIP_SYMBOL(g_px));
  hipGetSymbolAddress((void**)&pg, HIP_SYMBOL(g_pg));
  hipGetSymbolAddress((void**)&pu, HIP_SYMBOL(g_pu));
  hipGetSymbolAddress((void**)&pd, HIP_SYMBOL(g_pd));

  dim3 blk256(256, 1, 1);
  pack_split<<<2048, blk256, 0, stream>>>(x,    px, DIM,    (TOTAL * DIM) / 4);
  pack_split<<<2048, blk256, 0, stream>>>(gate, pg, DIM,    (NE * HIDDEN * DIM) / 4);
  pack_split<<<2048, blk256, 0, stream>>>(up,   pu, DIM,    (NE * HIDDEN * DIM) / 4);
  pack_split<<<2048, blk256, 0, stream>>>(down, pd, HIDDEN, (NE * DIM * HIDDEN) / 4);

  moe_s1<<<dim3(TOTAL / BM, HIDDEN / BN, NE), dim3(512, 1, 1), 0, stream>>>(cnts);
  moe_s2<<<dim3(TOTAL / BM, DIM / BN, NE), blk256, 0, stream>>>(cnts, out);
}